// Round 9
// baseline (1441.545 us; speedup 1.0000x reference)
//
#include <hip/hip_runtime.h>

#define N_ROWS 32768
#define D_DIM  512
#define P_DIM  4096

#define OUT_LOGITS (32768LL * 512)
#define OUT_CVAE   (OUT_LOGITS + 32768LL * 4096)
#define OUT_PROT   (OUT_CVAE + 1)

typedef __attribute__((ext_vector_type(8))) short short8;
typedef __attribute__((ext_vector_type(4))) float f32x4;

__device__ __forceinline__ unsigned short f2bf(float f) {
  unsigned u = __float_as_uint(f);
  u = (u + 0x7FFFu + ((u >> 16) & 1u)) >> 16;
  return (unsigned short)u;
}

__device__ __forceinline__ void gload16(const void* g, void* l) {
  __builtin_amdgcn_global_load_lds((const __attribute__((address_space(1))) void*)g,
                                   (__attribute__((address_space(3))) void*)l,
                                   16, 0, 0);
}

// ---------------------------------------------------------------------------
// Prep: row L2-norm; bf16 copy in 256-row-tile fragment-major layout
// (identical to R8, verified): elem[(tile*16+kt)*8192 + (fr*64+kq*16+r)*8 + e]
// with row = tile*256 + fr*16 + r, k = kt*32 + kq*8 + e.
// xn uses non-temporal stores (write-once stream stays out of cache).
// ---------------------------------------------------------------------------
template <int NORM>
__global__ __launch_bounds__(256) void prep_kernel(const float* __restrict__ in,
                                                   float* __restrict__ outf,
                                                   unsigned short* __restrict__ outb,
                                                   float* __restrict__ n2) {
  int wave = threadIdx.x >> 6, lane = threadIdx.x & 63;
  int row  = blockIdx.x * 4 + wave;
  const float* p = in + (size_t)row * D_DIM + lane * 8;
  float4 v0 = *(const float4*)p;
  float4 v1 = *(const float4*)(p + 4);
  float ss = v0.x*v0.x + v0.y*v0.y + v0.z*v0.z + v0.w*v0.w
           + v1.x*v1.x + v1.y*v1.y + v1.z*v1.z + v1.w*v1.w;
#pragma unroll
  for (int m = 1; m < 64; m <<= 1) ss += __shfl_xor(ss, m);
  if (NORM) {
    float rinv = 1.0f / fmaxf(sqrtf(ss), 1e-12f);
    v0.x *= rinv; v0.y *= rinv; v0.z *= rinv; v0.w *= rinv;
    v1.x *= rinv; v1.y *= rinv; v1.z *= rinv; v1.w *= rinv;
    f32x4* qp = (f32x4*)(outf + (size_t)row * D_DIM + lane * 8);
    f32x4 a0 = {v0.x, v0.y, v0.z, v0.w};
    f32x4 a1 = {v1.x, v1.y, v1.z, v1.w};
    __builtin_nontemporal_store(a0, qp);
    __builtin_nontemporal_store(a1, qp + 1);
  } else {
    if (lane == 0) n2[row] = ss;
  }
  uint4 b;
  b.x = (unsigned)f2bf(v0.x) | ((unsigned)f2bf(v0.y) << 16);
  b.y = (unsigned)f2bf(v0.z) | ((unsigned)f2bf(v0.w) << 16);
  b.z = (unsigned)f2bf(v1.x) | ((unsigned)f2bf(v1.y) << 16);
  b.w = (unsigned)f2bf(v1.z) | ((unsigned)f2bf(v1.w) << 16);
  int tile = row >> 8, fr = (row >> 4) & 15, r = row & 15;
  size_t dst = (size_t)(tile * 16 + (lane >> 2)) * 8192
             + (size_t)((fr * 64 + (lane & 3) * 16 + r) * 8);
  *(uint4*)(outb + dst) = b;
}

__global__ __launch_bounds__(256) void init_mins(unsigned int* __restrict__ p, int n) {
  int i = blockIdx.x * 256 + threadIdx.x;
  if (i < n) p[i] = 0x7F800000u;   // +inf
}

// ---------------------------------------------------------------------------
// 256x256-tile GEMM, BK=32, 8 waves, DOUBLE-buffered LDS (2 x 32 KB = 64 KB)
// -> 2 blocks/CU (16 waves/CU TLP). One s_barrier per K-step; vmcnt(0) at
// step top waits a stage issued a full step earlier (co-resident block covers
// the residual). WAR-safe: stg(kt+1) writes the buffer read at kt-1; every
// wave past barrier(kt) completed those reads (lgkmcnt-waited before its
// MFMA(kt-1)). Stage issued right after the barrier for max latency cover.
// A = W-frag, B = xn-frag -> lane's f32x4 spans 4 consecutive logits cols ->
// NT dwordx4 stores. Fused d2 epilogue -> global atomicMin (deterministic).
// ---------------------------------------------------------------------------
__global__ __launch_bounds__(512, 4) void gemm_fused(
    const unsigned short* __restrict__ Wb, const unsigned short* __restrict__ Xb,
    const float* __restrict__ w2, float* __restrict__ Cout,
    unsigned int* __restrict__ rowmin_g, unsigned int* __restrict__ colmin_g) {
  __shared__ __align__(16) unsigned short SA[2][8192];   // W tile 256x32
  __shared__ __align__(16) unsigned short SB[2][8192];   // x tile 256x32
  __shared__ unsigned int rowmin_u[256];                 // per x-row
  __shared__ unsigned int colmin_u[256];                 // per w-col

  const int tid = threadIdx.x;
  const int wave = tid >> 6, lane = tid & 63;
  const int q = lane >> 4, r16 = lane & 15;
  const int ww = wave & 1, wx = wave >> 1;   // 2 w-groups x 4 x-groups

  const int b = blockIdx.x;
  const int tw = (b & 7) * 2 + ((b >> 3) & 1);   // 0..15 (XCD-pinned W pair)
  const int tx = b >> 4;                         // 0..127
  const int w0 = tw * 256, x0 = tx * 256;

  if (tid < 256) { rowmin_u[tid] = 0x7F800000u; colmin_u[tid] = 0x7F800000u; }

  const unsigned short* Wg = Wb + (size_t)(tw * 16) * 8192;
  const unsigned short* Xg = Xb + (size_t)(tx * 16) * 8192;

  f32x4 acc[8][4];
#pragma unroll
  for (int m = 0; m < 8; ++m)
#pragma unroll
    for (int n = 0; n < 4; ++n) acc[m][n] = (f32x4){0.f, 0.f, 0.f, 0.f};

  auto stg = [&](int kt, int bu) {   // 4 gload_lds per thread (2 W + 2 X)
#pragma unroll
    for (int i = 0; i < 2; ++i) {
      int c = (tid + 512 * i) * 8;
      gload16(Wg + (size_t)kt * 8192 + c, &SA[bu][0] + c);
      gload16(Xg + (size_t)kt * 8192 + c, &SB[bu][0] + c);
    }
  };

  stg(0, 0);

#pragma unroll
  for (int kt = 0; kt < 16; ++kt) {
    const int cur = kt & 1;
    asm volatile("s_waitcnt vmcnt(0)" ::: "memory");   // stg(kt), issued 1 step ago
    __builtin_amdgcn_s_barrier();
    if (kt < 15) stg(kt + 1, cur ^ 1);                 // buffer read at kt-1: safe

    short8 af[8], bf[4];
#pragma unroll
    for (int m = 0; m < 8; ++m)
      af[m] = *(const short8*)(&SA[cur][0] + ((ww * 8 + m) * 64 + lane) * 8);
#pragma unroll
    for (int n = 0; n < 4; ++n)
      bf[n] = *(const short8*)(&SB[cur][0] + ((wx * 4 + n) * 64 + lane) * 8);

    __builtin_amdgcn_s_setprio(1);
#pragma unroll
    for (int m = 0; m < 8; ++m)
#pragma unroll
      for (int n = 0; n < 4; ++n)
        acc[m][n] = __builtin_amdgcn_mfma_f32_16x16x32_bf16(af[m], bf[n], acc[m][n], 0, 0, 0);
    __builtin_amdgcn_s_setprio(0);
  }

  // ---- epilogue: non-temporal float4 stores + fused d2 mins ----
  float rmin[4];                      // per n (x-rows)
  float cmin[8][4];                   // per m,j (w-cols)
#pragma unroll
  for (int n = 0; n < 4; ++n) rmin[n] = 1e30f;
#pragma unroll
  for (int m = 0; m < 8; ++m)
#pragma unroll
    for (int j = 0; j < 4; ++j) cmin[m][j] = 1e30f;

  const float* w2p = w2 + w0 + ww * 128;
#pragma unroll
  for (int m = 0; m < 8; ++m) {
    float4 w2v = *(const float4*)(w2p + m * 16 + q * 4);
    const size_t wcol = (size_t)(w0 + ww * 128 + m * 16 + q * 4);
#pragma unroll
    for (int n = 0; n < 4; ++n) {
      f32x4 c = acc[m][n];
      int xr = x0 + wx * 64 + n * 16 + r16;
      __builtin_nontemporal_store(c, (f32x4*)&Cout[(size_t)xr * P_DIM + wcol]);
      float d0 = fmaxf(fmaf(-2.f, c[0], 1.f + w2v.x), 0.f);
      float d1 = fmaxf(fmaf(-2.f, c[1], 1.f + w2v.y), 0.f);
      float d2 = fmaxf(fmaf(-2.f, c[2], 1.f + w2v.z), 0.f);
      float d3 = fmaxf(fmaf(-2.f, c[3], 1.f + w2v.w), 0.f);
      rmin[n] = fminf(rmin[n], fminf(fminf(d0, d1), fminf(d2, d3)));
      cmin[m][0] = fminf(cmin[m][0], d0);
      cmin[m][1] = fminf(cmin[m][1], d1);
      cmin[m][2] = fminf(cmin[m][2], d2);
      cmin[m][3] = fminf(cmin[m][3], d3);
    }
  }
  // row-min: reduce across q (same x-row for equal r16)
#pragma unroll
  for (int mask = 16; mask <= 32; mask <<= 1)
#pragma unroll
    for (int n = 0; n < 4; ++n)
      rmin[n] = fminf(rmin[n], __shfl_xor(rmin[n], mask));
  if (q == 0) {
#pragma unroll
    for (int n = 0; n < 4; ++n)
      atomicMin(&rowmin_u[wx * 64 + n * 16 + r16], __float_as_uint(rmin[n]));
  }
  // col-min: reduce across r16 (same w-col for equal q)
#pragma unroll
  for (int mask = 1; mask <= 8; mask <<= 1)
#pragma unroll
    for (int m = 0; m < 8; ++m)
#pragma unroll
      for (int j = 0; j < 4; ++j)
        cmin[m][j] = fminf(cmin[m][j], __shfl_xor(cmin[m][j], mask));
  if (r16 == 0) {
#pragma unroll
    for (int m = 0; m < 8; ++m)
#pragma unroll
      for (int j = 0; j < 4; ++j)
        atomicMin(&colmin_u[ww * 128 + m * 16 + q * 4 + j], __float_as_uint(cmin[m][j]));
  }
  __syncthreads();
  if (tid < 256) atomicMin(&rowmin_g[x0 + tid], rowmin_u[tid]);
  else           atomicMin(&colmin_g[w0 + (tid - 256)], colmin_u[tid - 256]);
}

// ---------------------------------------------------------------------------
// sqrt of final mins + fixed-order block sums.
// ---------------------------------------------------------------------------
__global__ __launch_bounds__(256) void minsqrt_sum(const unsigned int* __restrict__ mins,
                                                   float* __restrict__ out) {
  int idx = blockIdx.x * 256 + threadIdx.x;
  float s = sqrtf(__uint_as_float(mins[idx]));
#pragma unroll
  for (int mask = 1; mask < 64; mask <<= 1) s += __shfl_xor(s, mask);
  __shared__ float wsum[4];
  int wave = threadIdx.x >> 6, lane = threadIdx.x & 63;
  if (lane == 0) wsum[wave] = s;
  __syncthreads();
  if (threadIdx.x == 0) out[blockIdx.x] = wsum[0] + wsum[1] + wsum[2] + wsum[3];
}

__global__ void finalize_kernel(const float* __restrict__ rowp, const float* __restrict__ colp,
                                const float* __restrict__ recon, const float* __restrict__ kl,
                                const float* __restrict__ mmd, float* __restrict__ out) {
  int lane = threadIdx.x;  // 64 threads
  float rs = rowp[lane] + rowp[lane + 64];
  float cs = (lane < 16) ? colp[lane] : 0.0f;
#pragma unroll
  for (int mask = 1; mask < 64; mask <<= 1) {
    rs += __shfl_xor(rs, mask);
    cs += __shfl_xor(cs, mask);
  }
  if (lane == 0) {
    out[OUT_CVAE] = recon[0] + 0.5f * kl[0] + mmd[0];
    out[OUT_PROT] = 0.5f * (rs / (float)N_ROWS) + 0.5f * (cs / (float)P_DIM);
  }
}

extern "C" void kernel_launch(void* const* d_in, const int* in_sizes, int n_in,
                              void* d_out, int out_size, void* d_ws, size_t ws_size,
                              hipStream_t stream) {
  const float* x     = (const float*)d_in[0];
  const float* W     = (const float*)d_in[1];
  const float* recon = (const float*)d_in[2];
  const float* kl    = (const float*)d_in[3];
  const float* mmd   = (const float*)d_in[4];
  float* out    = (float*)d_out;
  float* xn     = out;
  float* logits = out + OUT_LOGITS;

  char* ws = (char*)d_ws;
  unsigned short* Xbf = (unsigned short*)ws;                 // 33,554,432 B
  unsigned short* Wbf = (unsigned short*)(ws + 33554432);    //  4,194,304 B
  float* w2          = (float*)(ws + 37748736);              //     16,384 B
  unsigned int* rmg  = (unsigned int*)(ws + 37765120);       //    131,072 B (32768)
  unsigned int* cmg  = (unsigned int*)(ws + 37896192);       //     16,384 B (4096)
  float* rowsums     = (float*)(ws + 37912576);              //        512 B (128)
  float* colsums     = (float*)(ws + 37913088);              //         64 B (16)

  init_mins<<<(32768 + 4096 + 255) / 256, 256, 0, stream>>>(rmg, 32768 + 4096);
  prep_kernel<1><<<N_ROWS / 4, 256, 0, stream>>>(x, xn, Xbf, nullptr);
  prep_kernel<0><<<P_DIM / 4, 256, 0, stream>>>(W, nullptr, Wbf, w2);
  gemm_fused<<<(N_ROWS / 256) * (P_DIM / 256), 512, 0, stream>>>(
      Wbf, Xbf, w2, logits, rmg, cmg);
  minsqrt_sum<<<N_ROWS / 256, 256, 0, stream>>>(rmg, rowsums);
  minsqrt_sum<<<P_DIM / 256, 256, 0, stream>>>(cmg, colsums);
  finalize_kernel<<<1, 64, 0, stream>>>(rowsums, colsums, recon, kl, mmd, out);
}

// Round 10
// 302.548 us; speedup vs baseline: 4.7647x; 4.7647x over previous
//
#include <hip/hip_runtime.h>

#define N_ROWS 32768
#define D_DIM  512
#define P_DIM  4096

#define OUT_LOGITS (32768LL * 512)
#define OUT_CVAE   (OUT_LOGITS + 32768LL * 4096)
#define OUT_PROT   (OUT_CVAE + 1)

typedef __attribute__((ext_vector_type(8))) short short8;
typedef __attribute__((ext_vector_type(4))) float f32x4;

__device__ __forceinline__ unsigned short f2bf(float f) {
  unsigned u = __float_as_uint(f);
  u = (u + 0x7FFFu + ((u >> 16) & 1u)) >> 16;
  return (unsigned short)u;
}

__device__ __forceinline__ void gload16(const void* g, void* l) {
  __builtin_amdgcn_global_load_lds((const __attribute__((address_space(1))) void*)g,
                                   (__attribute__((address_space(3))) void*)l,
                                   16, 0, 0);
}

// ---------------------------------------------------------------------------
// Prep: row L2-norm; bf16 copy in 256-row-tile fragment-major layout
// (identical to R8, verified): elem[(tile*16+kt)*8192 + (fr*64+kq*16+r)*8 + e]
// with row = tile*256 + fr*16 + r, k = kt*32 + kq*8 + e.
// xn uses non-temporal stores (write-once stream stays out of cache).
// ---------------------------------------------------------------------------
template <int NORM>
__global__ __launch_bounds__(256) void prep_kernel(const float* __restrict__ in,
                                                   float* __restrict__ outf,
                                                   unsigned short* __restrict__ outb,
                                                   float* __restrict__ n2) {
  int wave = threadIdx.x >> 6, lane = threadIdx.x & 63;
  int row  = blockIdx.x * 4 + wave;
  const float* p = in + (size_t)row * D_DIM + lane * 8;
  float4 v0 = *(const float4*)p;
  float4 v1 = *(const float4*)(p + 4);
  float ss = v0.x*v0.x + v0.y*v0.y + v0.z*v0.z + v0.w*v0.w
           + v1.x*v1.x + v1.y*v1.y + v1.z*v1.z + v1.w*v1.w;
#pragma unroll
  for (int m = 1; m < 64; m <<= 1) ss += __shfl_xor(ss, m);
  if (NORM) {
    float rinv = 1.0f / fmaxf(sqrtf(ss), 1e-12f);
    v0.x *= rinv; v0.y *= rinv; v0.z *= rinv; v0.w *= rinv;
    v1.x *= rinv; v1.y *= rinv; v1.z *= rinv; v1.w *= rinv;
    f32x4* qp = (f32x4*)(outf + (size_t)row * D_DIM + lane * 8);
    f32x4 a0 = {v0.x, v0.y, v0.z, v0.w};
    f32x4 a1 = {v1.x, v1.y, v1.z, v1.w};
    __builtin_nontemporal_store(a0, qp);
    __builtin_nontemporal_store(a1, qp + 1);
  } else {
    if (lane == 0) n2[row] = ss;
  }
  uint4 b;
  b.x = (unsigned)f2bf(v0.x) | ((unsigned)f2bf(v0.y) << 16);
  b.y = (unsigned)f2bf(v0.z) | ((unsigned)f2bf(v0.w) << 16);
  b.z = (unsigned)f2bf(v1.x) | ((unsigned)f2bf(v1.y) << 16);
  b.w = (unsigned)f2bf(v1.z) | ((unsigned)f2bf(v1.w) << 16);
  int tile = row >> 8, fr = (row >> 4) & 15, r = row & 15;
  size_t dst = (size_t)(tile * 16 + (lane >> 2)) * 8192
             + (size_t)((fr * 64 + (lane & 3) * 16 + r) * 8);
  *(uint4*)(outb + dst) = b;
}

__global__ __launch_bounds__(256) void init_mins(unsigned int* __restrict__ p, int n) {
  int i = blockIdx.x * 256 + threadIdx.x;
  if (i < n) p[i] = 0x7F800000u;   // +inf
}

// ---------------------------------------------------------------------------
// 256x256-tile GEMM, BK=32, 8 waves, DOUBLE-buffered LDS (2 x 32 KB = 64 KB)
// -> 2 blocks/CU by LDS (66 KB each). __launch_bounds__(512,2): VGPR cap 256
// (NO SPILL — R9's (512,4) capped at 128 and spilled acc to scratch, 5 GB of
// scratch writes). One s_barrier per K-step; vmcnt(0) at step top waits a
// stage issued a full step earlier; co-resident block covers the residual.
// WAR-safe: stg(kt+1) writes the buffer read at kt-1.
// A = W-frag, B = xn-frag -> lane's f32x4 spans 4 consecutive logits cols ->
// NT dwordx4 stores. Fused d2 epilogue -> global atomicMin (deterministic).
// ---------------------------------------------------------------------------
__global__ __launch_bounds__(512, 2) void gemm_fused(
    const unsigned short* __restrict__ Wb, const unsigned short* __restrict__ Xb,
    const float* __restrict__ w2, float* __restrict__ Cout,
    unsigned int* __restrict__ rowmin_g, unsigned int* __restrict__ colmin_g) {
  __shared__ __align__(16) unsigned short SA[2][8192];   // W tile 256x32
  __shared__ __align__(16) unsigned short SB[2][8192];   // x tile 256x32
  __shared__ unsigned int rowmin_u[256];                 // per x-row
  __shared__ unsigned int colmin_u[256];                 // per w-col

  const int tid = threadIdx.x;
  const int wave = tid >> 6, lane = tid & 63;
  const int q = lane >> 4, r16 = lane & 15;
  const int ww = wave & 1, wx = wave >> 1;   // 2 w-groups x 4 x-groups

  const int b = blockIdx.x;
  const int tw = (b & 7) * 2 + ((b >> 3) & 1);   // 0..15 (XCD-pinned W pair)
  const int tx = b >> 4;                         // 0..127
  const int w0 = tw * 256, x0 = tx * 256;

  if (tid < 256) { rowmin_u[tid] = 0x7F800000u; colmin_u[tid] = 0x7F800000u; }

  const unsigned short* Wg = Wb + (size_t)(tw * 16) * 8192;
  const unsigned short* Xg = Xb + (size_t)(tx * 16) * 8192;

  f32x4 acc[8][4];
#pragma unroll
  for (int m = 0; m < 8; ++m)
#pragma unroll
    for (int n = 0; n < 4; ++n) acc[m][n] = (f32x4){0.f, 0.f, 0.f, 0.f};

  auto stg = [&](int kt, int bu) {   // 4 gload_lds per thread (2 W + 2 X)
#pragma unroll
    for (int i = 0; i < 2; ++i) {
      int c = (tid + 512 * i) * 8;
      gload16(Wg + (size_t)kt * 8192 + c, &SA[bu][0] + c);
      gload16(Xg + (size_t)kt * 8192 + c, &SB[bu][0] + c);
    }
  };

  stg(0, 0);

#pragma unroll
  for (int kt = 0; kt < 16; ++kt) {
    const int cur = kt & 1;
    asm volatile("s_waitcnt vmcnt(0)" ::: "memory");   // stg(kt), issued 1 step ago
    __builtin_amdgcn_s_barrier();
    if (kt < 15) stg(kt + 1, cur ^ 1);                 // buffer read at kt-1: safe

    short8 af[8], bf[4];
#pragma unroll
    for (int m = 0; m < 8; ++m)
      af[m] = *(const short8*)(&SA[cur][0] + ((ww * 8 + m) * 64 + lane) * 8);
#pragma unroll
    for (int n = 0; n < 4; ++n)
      bf[n] = *(const short8*)(&SB[cur][0] + ((wx * 4 + n) * 64 + lane) * 8);

    __builtin_amdgcn_s_setprio(1);
#pragma unroll
    for (int m = 0; m < 8; ++m)
#pragma unroll
      for (int n = 0; n < 4; ++n)
        acc[m][n] = __builtin_amdgcn_mfma_f32_16x16x32_bf16(af[m], bf[n], acc[m][n], 0, 0, 0);
    __builtin_amdgcn_s_setprio(0);
  }

  // ---- epilogue: non-temporal float4 stores + fused d2 mins ----
  float rmin[4];                      // per n (x-rows)
  float cmin[8][4];                   // per m,j (w-cols)
#pragma unroll
  for (int n = 0; n < 4; ++n) rmin[n] = 1e30f;
#pragma unroll
  for (int m = 0; m < 8; ++m)
#pragma unroll
    for (int j = 0; j < 4; ++j) cmin[m][j] = 1e30f;

  const float* w2p = w2 + w0 + ww * 128;
#pragma unroll
  for (int m = 0; m < 8; ++m) {
    float4 w2v = *(const float4*)(w2p + m * 16 + q * 4);
    const size_t wcol = (size_t)(w0 + ww * 128 + m * 16 + q * 4);
#pragma unroll
    for (int n = 0; n < 4; ++n) {
      f32x4 c = acc[m][n];
      int xr = x0 + wx * 64 + n * 16 + r16;
      __builtin_nontemporal_store(c, (f32x4*)&Cout[(size_t)xr * P_DIM + wcol]);
      float d0 = fmaxf(fmaf(-2.f, c[0], 1.f + w2v.x), 0.f);
      float d1 = fmaxf(fmaf(-2.f, c[1], 1.f + w2v.y), 0.f);
      float d2 = fmaxf(fmaf(-2.f, c[2], 1.f + w2v.z), 0.f);
      float d3 = fmaxf(fmaf(-2.f, c[3], 1.f + w2v.w), 0.f);
      rmin[n] = fminf(rmin[n], fminf(fminf(d0, d1), fminf(d2, d3)));
      cmin[m][0] = fminf(cmin[m][0], d0);
      cmin[m][1] = fminf(cmin[m][1], d1);
      cmin[m][2] = fminf(cmin[m][2], d2);
      cmin[m][3] = fminf(cmin[m][3], d3);
    }
  }
  // row-min: reduce across q (same x-row for equal r16)
#pragma unroll
  for (int mask = 16; mask <= 32; mask <<= 1)
#pragma unroll
    for (int n = 0; n < 4; ++n)
      rmin[n] = fminf(rmin[n], __shfl_xor(rmin[n], mask));
  if (q == 0) {
#pragma unroll
    for (int n = 0; n < 4; ++n)
      atomicMin(&rowmin_u[wx * 64 + n * 16 + r16], __float_as_uint(rmin[n]));
  }
  // col-min: reduce across r16 (same w-col for equal q)
#pragma unroll
  for (int mask = 1; mask <= 8; mask <<= 1)
#pragma unroll
    for (int m = 0; m < 8; ++m)
#pragma unroll
      for (int j = 0; j < 4; ++j)
        cmin[m][j] = fminf(cmin[m][j], __shfl_xor(cmin[m][j], mask));
  if (r16 == 0) {
#pragma unroll
    for (int m = 0; m < 8; ++m)
#pragma unroll
      for (int j = 0; j < 4; ++j)
        atomicMin(&colmin_u[ww * 128 + m * 16 + q * 4 + j], __float_as_uint(cmin[m][j]));
  }
  __syncthreads();
  if (tid < 256) atomicMin(&rowmin_g[x0 + tid], rowmin_u[tid]);
  else           atomicMin(&colmin_g[w0 + (tid - 256)], colmin_u[tid - 256]);
}

// ---------------------------------------------------------------------------
// sqrt of final mins + fixed-order block sums.
// ---------------------------------------------------------------------------
__global__ __launch_bounds__(256) void minsqrt_sum(const unsigned int* __restrict__ mins,
                                                   float* __restrict__ out) {
  int idx = blockIdx.x * 256 + threadIdx.x;
  float s = sqrtf(__uint_as_float(mins[idx]));
#pragma unroll
  for (int mask = 1; mask < 64; mask <<= 1) s += __shfl_xor(s, mask);
  __shared__ float wsum[4];
  int wave = threadIdx.x >> 6, lane = threadIdx.x & 63;
  if (lane == 0) wsum[wave] = s;
  __syncthreads();
  if (threadIdx.x == 0) out[blockIdx.x] = wsum[0] + wsum[1] + wsum[2] + wsum[3];
}

__global__ void finalize_kernel(const float* __restrict__ rowp, const float* __restrict__ colp,
                                const float* __restrict__ recon, const float* __restrict__ kl,
                                const float* __restrict__ mmd, float* __restrict__ out) {
  int lane = threadIdx.x;  // 64 threads
  float rs = rowp[lane] + rowp[lane + 64];
  float cs = (lane < 16) ? colp[lane] : 0.0f;
#pragma unroll
  for (int mask = 1; mask < 64; mask <<= 1) {
    rs += __shfl_xor(rs, mask);
    cs += __shfl_xor(cs, mask);
  }
  if (lane == 0) {
    out[OUT_CVAE] = recon[0] + 0.5f * kl[0] + mmd[0];
    out[OUT_PROT] = 0.5f * (rs / (float)N_ROWS) + 0.5f * (cs / (float)P_DIM);
  }
}

extern "C" void kernel_launch(void* const* d_in, const int* in_sizes, int n_in,
                              void* d_out, int out_size, void* d_ws, size_t ws_size,
                              hipStream_t stream) {
  const float* x     = (const float*)d_in[0];
  const float* W     = (const float*)d_in[1];
  const float* recon = (const float*)d_in[2];
  const float* kl    = (const float*)d_in[3];
  const float* mmd   = (const float*)d_in[4];
  float* out    = (float*)d_out;
  float* xn     = out;
  float* logits = out + OUT_LOGITS;

  char* ws = (char*)d_ws;
  unsigned short* Xbf = (unsigned short*)ws;                 // 33,554,432 B
  unsigned short* Wbf = (unsigned short*)(ws + 33554432);    //  4,194,304 B
  float* w2          = (float*)(ws + 37748736);              //     16,384 B
  unsigned int* rmg  = (unsigned int*)(ws + 37765120);       //    131,072 B (32768)
  unsigned int* cmg  = (unsigned int*)(ws + 37896192);       //     16,384 B (4096)
  float* rowsums     = (float*)(ws + 37912576);              //        512 B (128)
  float* colsums     = (float*)(ws + 37913088);              //         64 B (16)

  init_mins<<<(32768 + 4096 + 255) / 256, 256, 0, stream>>>(rmg, 32768 + 4096);
  prep_kernel<1><<<N_ROWS / 4, 256, 0, stream>>>(x, xn, Xbf, nullptr);
  prep_kernel<0><<<P_DIM / 4, 256, 0, stream>>>(W, nullptr, Wbf, w2);
  gemm_fused<<<(N_ROWS / 256) * (P_DIM / 256), 512, 0, stream>>>(
      Wbf, Xbf, w2, logits, rmg, cmg);
  minsqrt_sum<<<N_ROWS / 256, 256, 0, stream>>>(rmg, rowsums);
  minsqrt_sum<<<P_DIM / 256, 256, 0, stream>>>(cmg, colsums);
  finalize_kernel<<<1, 64, 0, stream>>>(rowsums, colsums, recon, kl, mmd, out);
}

// Round 11
// 259.197 us; speedup vs baseline: 5.5616x; 1.1673x over previous
//
#include <hip/hip_runtime.h>

#define N_ROWS 32768
#define D_DIM  512
#define P_DIM  4096

#define OUT_LOGITS (32768LL * 512)
#define OUT_CVAE   (OUT_LOGITS + 32768LL * 4096)
#define OUT_PROT   (OUT_CVAE + 1)

typedef __attribute__((ext_vector_type(8))) short short8;
typedef __attribute__((ext_vector_type(4))) float f32x4;

__device__ __forceinline__ unsigned short f2bf(float f) {
  unsigned u = __float_as_uint(f);
  u = (u + 0x7FFFu + ((u >> 16) & 1u)) >> 16;
  return (unsigned short)u;
}

// ---------------------------------------------------------------------------
// Prep: row L2-norm; bf16 copy in 128-row-tile fragment-major layout
// (R5/R7 verified): elem[(tile*16+kt)*4096 + (fr*64 + kq*16 + r)*8 + e]
// with row = tile*128 + fr*16 + r, k = kt*32 + kq*8 + e.
// One wave per row; lane j holds k = j*8..j*8+7 (kt=j>>2, kq=j&3).
// xn uses non-temporal stores (write-once stream stays out of cache).
// ---------------------------------------------------------------------------
template <int NORM>
__global__ __launch_bounds__(256) void prep_kernel(const float* __restrict__ in,
                                                   float* __restrict__ outf,
                                                   unsigned short* __restrict__ outb,
                                                   float* __restrict__ n2) {
  int wave = threadIdx.x >> 6, lane = threadIdx.x & 63;
  int row  = blockIdx.x * 4 + wave;
  const float* p = in + (size_t)row * D_DIM + lane * 8;
  float4 v0 = *(const float4*)p;
  float4 v1 = *(const float4*)(p + 4);
  float ss = v0.x*v0.x + v0.y*v0.y + v0.z*v0.z + v0.w*v0.w
           + v1.x*v1.x + v1.y*v1.y + v1.z*v1.z + v1.w*v1.w;
#pragma unroll
  for (int m = 1; m < 64; m <<= 1) ss += __shfl_xor(ss, m);
  if (NORM) {
    float rinv = 1.0f / fmaxf(sqrtf(ss), 1e-12f);
    v0.x *= rinv; v0.y *= rinv; v0.z *= rinv; v0.w *= rinv;
    v1.x *= rinv; v1.y *= rinv; v1.z *= rinv; v1.w *= rinv;
    f32x4* qp = (f32x4*)(outf + (size_t)row * D_DIM + lane * 8);
    f32x4 a0 = {v0.x, v0.y, v0.z, v0.w};
    f32x4 a1 = {v1.x, v1.y, v1.z, v1.w};
    __builtin_nontemporal_store(a0, qp);
    __builtin_nontemporal_store(a1, qp + 1);
  } else {
    if (lane == 0) n2[row] = ss;
  }
  uint4 b;
  b.x = (unsigned)f2bf(v0.x) | ((unsigned)f2bf(v0.y) << 16);
  b.y = (unsigned)f2bf(v0.z) | ((unsigned)f2bf(v0.w) << 16);
  b.z = (unsigned)f2bf(v1.x) | ((unsigned)f2bf(v1.y) << 16);
  b.w = (unsigned)f2bf(v1.z) | ((unsigned)f2bf(v1.w) << 16);
  int tile = row >> 7, fr = (row >> 4) & 7, r = row & 15;
  size_t dst = (size_t)(tile * 16 + (lane >> 2)) * 4096
             + (size_t)((fr * 64 + (lane & 3) * 16 + r) * 8);
  *(uint4*)(outb + dst) = b;
}

__global__ __launch_bounds__(256) void init_mins(unsigned int* __restrict__ p, int n) {
  int i = blockIdx.x * 256 + threadIdx.x;
  if (i < n) p[i] = 0x7F800000u;   // +inf
}

// ---------------------------------------------------------------------------
// 128x128-tile GEMM with NO LDS STAGING and NO BARRIERS: both operands are in
// fragment-major layout, so each wave loads its MFMA fragments directly
// global->VGPR (lane-contiguous dwordx4, 1 KB/frag, fully coalesced).
// 4 independent waves/block (2x2 -> each wave owns 64x64 output), 2-deep
// manual rotation (load kt+1 while MFMA kt) -> compiler emits counted vmcnt.
// Intra-block duplicate frag reads (2x per operand) are L1 hits (16 KB/kt).
// ~12 independent waves/CU hide latency without any lockstep.
// A = W-frag, B = xn-frag -> lane's f32x4 spans 4 consecutive logits cols ->
// NT dwordx4 stores. Fused d2 epilogue -> global atomicMin (deterministic).
// ---------------------------------------------------------------------------
__global__ __launch_bounds__(256) void gemm_fused(
    const unsigned short* __restrict__ Wb, const unsigned short* __restrict__ Xb,
    const float* __restrict__ w2, float* __restrict__ Cout,
    unsigned int* __restrict__ rowmin_g, unsigned int* __restrict__ colmin_g) {
  __shared__ unsigned int rowmin_u[128];                 // per x-row
  __shared__ unsigned int colmin_u[128];                 // per w-col

  const int tid = threadIdx.x;
  const int wave = tid >> 6, lane = tid & 63;
  const int q = lane >> 4, r16 = lane & 15;
  const int ww = wave >> 1, wx = wave & 1;   // 2 w-groups x 2 x-groups

  const int b = blockIdx.x;
  const int tw = (b & 7) * 4 + ((b >> 3) & 3);   // 0..31 (XCD-pinned W column)
  const int tx = b >> 5;                         // 0..255
  const int w0 = tw * 128, x0 = tx * 128;

  if (tid < 128) { rowmin_u[tid] = 0x7F800000u; colmin_u[tid] = 0x7F800000u; }

  const unsigned short* Wg = Wb + (size_t)tw * 65536;   // 16 kt x 4096 elems
  const unsigned short* Xg = Xb + (size_t)tx * 65536;

  f32x4 acc[4][4];
#pragma unroll
  for (int m = 0; m < 4; ++m)
#pragma unroll
    for (int n = 0; n < 4; ++n) acc[m][n] = (f32x4){0.f, 0.f, 0.f, 0.f};

  auto ldw = [&](int kt, int m) -> short8 {
    return *(const short8*)(Wg + kt * 4096 + ((ww * 4 + m) * 64 + lane) * 8);
  };
  auto ldx = [&](int kt, int n) -> short8 {
    return *(const short8*)(Xg + kt * 4096 + ((wx * 4 + n) * 64 + lane) * 8);
  };

  short8 wa[4], xa[4], wn[4], xn_[4];
#pragma unroll
  for (int m = 0; m < 4; ++m) { wa[m] = ldw(0, m); xa[m] = ldx(0, m); }

#pragma unroll
  for (int kt = 0; kt < 16; kt += 2) {
    // issue loads for kt+1 (independent of the MFMAs below)
#pragma unroll
    for (int m = 0; m < 4; ++m) { wn[m] = ldw(kt + 1, m); xn_[m] = ldx(kt + 1, m); }
    __builtin_amdgcn_s_setprio(1);
#pragma unroll
    for (int m = 0; m < 4; ++m)
#pragma unroll
      for (int n = 0; n < 4; ++n)
        acc[m][n] = __builtin_amdgcn_mfma_f32_16x16x32_bf16(wa[m], xa[n], acc[m][n], 0, 0, 0);
    __builtin_amdgcn_s_setprio(0);
    if (kt + 2 < 16) {
#pragma unroll
      for (int m = 0; m < 4; ++m) { wa[m] = ldw(kt + 2, m); xa[m] = ldx(kt + 2, m); }
    }
    __builtin_amdgcn_s_setprio(1);
#pragma unroll
    for (int m = 0; m < 4; ++m)
#pragma unroll
      for (int n = 0; n < 4; ++n)
        acc[m][n] = __builtin_amdgcn_mfma_f32_16x16x32_bf16(wn[m], xn_[n], acc[m][n], 0, 0, 0);
    __builtin_amdgcn_s_setprio(0);
  }

  // ---- epilogue: non-temporal float4 stores + fused d2 mins (R7 verbatim) --
  float rmin[4];                      // per n (x-rows)
  float cmin[4][4];                   // per m,j (w-cols)
#pragma unroll
  for (int n = 0; n < 4; ++n) rmin[n] = 1e30f;
#pragma unroll
  for (int m = 0; m < 4; ++m)
#pragma unroll
    for (int j = 0; j < 4; ++j) cmin[m][j] = 1e30f;

  const float* w2p = w2 + w0 + ww * 64;
#pragma unroll
  for (int m = 0; m < 4; ++m) {
    float4 w2v = *(const float4*)(w2p + m * 16 + q * 4);
    const size_t wcol = (size_t)(w0 + ww * 64 + m * 16 + q * 4);
#pragma unroll
    for (int n = 0; n < 4; ++n) {
      f32x4 c = acc[m][n];
      int xr = x0 + wx * 64 + n * 16 + r16;
      __builtin_nontemporal_store(c, (f32x4*)&Cout[(size_t)xr * P_DIM + wcol]);
      float d0 = fmaxf(fmaf(-2.f, c[0], 1.f + w2v.x), 0.f);
      float d1 = fmaxf(fmaf(-2.f, c[1], 1.f + w2v.y), 0.f);
      float d2 = fmaxf(fmaf(-2.f, c[2], 1.f + w2v.z), 0.f);
      float d3 = fmaxf(fmaf(-2.f, c[3], 1.f + w2v.w), 0.f);
      rmin[n] = fminf(rmin[n], fminf(fminf(d0, d1), fminf(d2, d3)));
      cmin[m][0] = fminf(cmin[m][0], d0);
      cmin[m][1] = fminf(cmin[m][1], d1);
      cmin[m][2] = fminf(cmin[m][2], d2);
      cmin[m][3] = fminf(cmin[m][3], d3);
    }
  }
  // row-min: reduce across q (same x-row for equal r16)
#pragma unroll
  for (int mask = 16; mask <= 32; mask <<= 1)
#pragma unroll
    for (int n = 0; n < 4; ++n)
      rmin[n] = fminf(rmin[n], __shfl_xor(rmin[n], mask));
  if (q == 0) {
#pragma unroll
    for (int n = 0; n < 4; ++n)
      atomicMin(&rowmin_u[wx * 64 + n * 16 + r16], __float_as_uint(rmin[n]));
  }
  // col-min: reduce across r16 (same w-col for equal q)
#pragma unroll
  for (int mask = 1; mask <= 8; mask <<= 1)
#pragma unroll
    for (int m = 0; m < 4; ++m)
#pragma unroll
      for (int j = 0; j < 4; ++j)
        cmin[m][j] = fminf(cmin[m][j], __shfl_xor(cmin[m][j], mask));
  if (r16 == 0) {
#pragma unroll
    for (int m = 0; m < 4; ++m)
#pragma unroll
      for (int j = 0; j < 4; ++j)
        atomicMin(&colmin_u[ww * 64 + m * 16 + q * 4 + j], __float_as_uint(cmin[m][j]));
  }
  __syncthreads();
  if (tid < 128) atomicMin(&rowmin_g[x0 + tid], rowmin_u[tid]);
  else           atomicMin(&colmin_g[w0 + (tid - 128)], colmin_u[tid - 128]);
}

// ---------------------------------------------------------------------------
// sqrt of final mins + fixed-order block sums.
// ---------------------------------------------------------------------------
__global__ __launch_bounds__(256) void minsqrt_sum(const unsigned int* __restrict__ mins,
                                                   float* __restrict__ out) {
  int idx = blockIdx.x * 256 + threadIdx.x;
  float s = sqrtf(__uint_as_float(mins[idx]));
#pragma unroll
  for (int mask = 1; mask < 64; mask <<= 1) s += __shfl_xor(s, mask);
  __shared__ float wsum[4];
  int wave = threadIdx.x >> 6, lane = threadIdx.x & 63;
  if (lane == 0) wsum[wave] = s;
  __syncthreads();
  if (threadIdx.x == 0) out[blockIdx.x] = wsum[0] + wsum[1] + wsum[2] + wsum[3];
}

__global__ void finalize_kernel(const float* __restrict__ rowp, const float* __restrict__ colp,
                                const float* __restrict__ recon, const float* __restrict__ kl,
                                const float* __restrict__ mmd, float* __restrict__ out) {
  int lane = threadIdx.x;  // 64 threads
  float rs = rowp[lane] + rowp[lane + 64];
  float cs = (lane < 16) ? colp[lane] : 0.0f;
#pragma unroll
  for (int mask = 1; mask < 64; mask <<= 1) {
    rs += __shfl_xor(rs, mask);
    cs += __shfl_xor(cs, mask);
  }
  if (lane == 0) {
    out[OUT_CVAE] = recon[0] + 0.5f * kl[0] + mmd[0];
    out[OUT_PROT] = 0.5f * (rs / (float)N_ROWS) + 0.5f * (cs / (float)P_DIM);
  }
}

extern "C" void kernel_launch(void* const* d_in, const int* in_sizes, int n_in,
                              void* d_out, int out_size, void* d_ws, size_t ws_size,
                              hipStream_t stream) {
  const float* x     = (const float*)d_in[0];
  const float* W     = (const float*)d_in[1];
  const float* recon = (const float*)d_in[2];
  const float* kl    = (const float*)d_in[3];
  const float* mmd   = (const float*)d_in[4];
  float* out    = (float*)d_out;
  float* xn     = out;
  float* logits = out + OUT_LOGITS;

  char* ws = (char*)d_ws;
  unsigned short* Xbf = (unsigned short*)ws;                 // 33,554,432 B
  unsigned short* Wbf = (unsigned short*)(ws + 33554432);    //  4,194,304 B
  float* w2          = (float*)(ws + 37748736);              //     16,384 B
  unsigned int* rmg  = (unsigned int*)(ws + 37765120);       //    131,072 B (32768)
  unsigned int* cmg  = (unsigned int*)(ws + 37896192);       //     16,384 B (4096)
  float* rowsums     = (float*)(ws + 37912576);              //        512 B (128)
  float* colsums     = (float*)(ws + 37913088);              //         64 B (16)

  init_mins<<<(32768 + 4096 + 255) / 256, 256, 0, stream>>>(rmg, 32768 + 4096);
  prep_kernel<1><<<N_ROWS / 4, 256, 0, stream>>>(x, xn, Xbf, nullptr);
  prep_kernel<0><<<P_DIM / 4, 256, 0, stream>>>(W, nullptr, Wbf, w2);
  gemm_fused<<<(N_ROWS / 128) * (P_DIM / 128), 256, 0, stream>>>(
      Wbf, Xbf, w2, logits, rmg, cmg);
  minsqrt_sum<<<N_ROWS / 256, 256, 0, stream>>>(rmg, rowsums);
  minsqrt_sum<<<P_DIM / 256, 256, 0, stream>>>(cmg, colsums);
  finalize_kernel<<<1, 64, 0, stream>>>(rowsums, colsums, recon, kl, mmd, out);
}

// Round 12
// 252.195 us; speedup vs baseline: 5.7160x; 1.0278x over previous
//
#include <hip/hip_runtime.h>

#define N_ROWS 32768
#define D_DIM  512
#define P_DIM  4096

#define OUT_LOGITS (32768LL * 512)
#define OUT_CVAE   (OUT_LOGITS + 32768LL * 4096)
#define OUT_PROT   (OUT_CVAE + 1)

typedef __attribute__((ext_vector_type(8))) short short8;
typedef __attribute__((ext_vector_type(4))) float f32x4;

__device__ __forceinline__ unsigned short f2bf(float f) {
  unsigned u = __float_as_uint(f);
  u = (u + 0x7FFFu + ((u >> 16) & 1u)) >> 16;
  return (unsigned short)u;
}

__device__ __forceinline__ void gload16(const void* g, void* l) {
  __builtin_amdgcn_global_load_lds((const __attribute__((address_space(1))) void*)g,
                                   (__attribute__((address_space(3))) void*)l,
                                   16, 0, 0);
}

// ---------------------------------------------------------------------------
// Prep: row L2-norm; bf16 copy in 128-row-tile fragment-major layout
// (R5/R7 verified). NORM=1 additionally initializes the global min arrays
// (blocks 0..127 -> rowmin, 128..143 -> colmin), replacing init_mins launch.
// xn uses non-temporal stores.
// ---------------------------------------------------------------------------
template <int NORM>
__global__ __launch_bounds__(256) void prep_kernel(const float* __restrict__ in,
                                                   float* __restrict__ outf,
                                                   unsigned short* __restrict__ outb,
                                                   float* __restrict__ n2,
                                                   unsigned int* __restrict__ rmg,
                                                   unsigned int* __restrict__ cmg) {
  if (NORM) {
    int bid = blockIdx.x;
    if (bid < 128)      rmg[bid * 256 + threadIdx.x] = 0x7F800000u;
    else if (bid < 144) cmg[(bid - 128) * 256 + threadIdx.x] = 0x7F800000u;
  }
  int wave = threadIdx.x >> 6, lane = threadIdx.x & 63;
  int row  = blockIdx.x * 4 + wave;
  const float* p = in + (size_t)row * D_DIM + lane * 8;
  float4 v0 = *(const float4*)p;
  float4 v1 = *(const float4*)(p + 4);
  float ss = v0.x*v0.x + v0.y*v0.y + v0.z*v0.z + v0.w*v0.w
           + v1.x*v1.x + v1.y*v1.y + v1.z*v1.z + v1.w*v1.w;
#pragma unroll
  for (int m = 1; m < 64; m <<= 1) ss += __shfl_xor(ss, m);
  if (NORM) {
    float rinv = 1.0f / fmaxf(sqrtf(ss), 1e-12f);
    v0.x *= rinv; v0.y *= rinv; v0.z *= rinv; v0.w *= rinv;
    v1.x *= rinv; v1.y *= rinv; v1.z *= rinv; v1.w *= rinv;
    f32x4* qp = (f32x4*)(outf + (size_t)row * D_DIM + lane * 8);
    f32x4 a0 = {v0.x, v0.y, v0.z, v0.w};
    f32x4 a1 = {v1.x, v1.y, v1.z, v1.w};
    __builtin_nontemporal_store(a0, qp);
    __builtin_nontemporal_store(a1, qp + 1);
  } else {
    if (lane == 0) n2[row] = ss;
  }
  uint4 b;
  b.x = (unsigned)f2bf(v0.x) | ((unsigned)f2bf(v0.y) << 16);
  b.y = (unsigned)f2bf(v0.z) | ((unsigned)f2bf(v0.w) << 16);
  b.z = (unsigned)f2bf(v1.x) | ((unsigned)f2bf(v1.y) << 16);
  b.w = (unsigned)f2bf(v1.z) | ((unsigned)f2bf(v1.w) << 16);
  int tile = row >> 7, fr = (row >> 4) & 7, r = row & 15;
  size_t dst = (size_t)(tile * 16 + (lane >> 2)) * 4096
             + (size_t)((fr * 64 + (lane & 3) * 16 + r) * 8);
  *(uint4*)(outb + dst) = b;
}

// ---------------------------------------------------------------------------
// 128x128-tile GEMM (R7 = measured best, 252 us): 4 waves, BK=32, TRIPLE-
// buffered LDS (3 x 16 KB), one s_barrier per K-step, counted vmcnt(4)
// (vmcnt(0) only at tail). Delta vs R7: stg(kt+2) issued BEFORE the frag
// ds_reads (earlier VMEM issue, same WAR safety: 3-buffer rotation).
// A = W-frag, B = xn-frag -> lane's f32x4 spans 4 consecutive logits cols ->
// NT dwordx4 stores. Fused d2 epilogue -> global atomicMin (deterministic).
// ---------------------------------------------------------------------------
__global__ __launch_bounds__(256, 3) void gemm_fused(
    const unsigned short* __restrict__ Wb, const unsigned short* __restrict__ Xb,
    const float* __restrict__ w2, float* __restrict__ Cout,
    unsigned int* __restrict__ rowmin_g, unsigned int* __restrict__ colmin_g) {
  __shared__ __align__(16) unsigned short SA[3][4096];   // W tile 128x32
  __shared__ __align__(16) unsigned short SB[3][4096];   // x tile 128x32
  __shared__ unsigned int rowmin_u[128];                 // per x-row
  __shared__ unsigned int colmin_u[128];                 // per w-col

  const int tid = threadIdx.x;
  const int wave = tid >> 6, lane = tid & 63;
  const int q = lane >> 4, r16 = lane & 15;
  const int ww = wave >> 1, wx = wave & 1;

  const int b = blockIdx.x;
  const int tw = (b & 7) * 4 + ((b >> 3) & 3);   // 0..31 (XCD-pinned W column)
  const int tx = b >> 5;                         // 0..255
  const int w0 = tw * 128, x0 = tx * 128;

  if (tid < 128) { rowmin_u[tid] = 0x7F800000u; colmin_u[tid] = 0x7F800000u; }

  const unsigned short* Wg = Wb + (size_t)(tw * 16) * 4096;
  const unsigned short* Xg = Xb + (size_t)(tx * 16) * 4096;

  f32x4 acc[4][4];
#pragma unroll
  for (int m = 0; m < 4; ++m)
#pragma unroll
    for (int n = 0; n < 4; ++n) acc[m][n] = (f32x4){0.f, 0.f, 0.f, 0.f};

  auto stg = [&](int kt, int bu) {   // 4 gload_lds per thread
#pragma unroll
    for (int i = 0; i < 2; ++i) {
      int c = (tid + 256 * i) * 8;
      gload16(Wg + (size_t)kt * 4096 + c, &SA[bu][0] + c);
      gload16(Xg + (size_t)kt * 4096 + c, &SB[bu][0] + c);
    }
  };

  stg(0, 0);
  stg(1, 1);

#pragma unroll
  for (int kt = 0; kt < 16; ++kt) {
    const int cur = kt % 3;
    if (kt < 15) { asm volatile("s_waitcnt vmcnt(4)" ::: "memory"); }
    else         { asm volatile("s_waitcnt vmcnt(0)" ::: "memory"); }
    __builtin_amdgcn_s_barrier();

    if (kt < 14) stg(kt + 2, (kt + 2) % 3);   // issue before frag reads

    short8 af[4], bf[4];
#pragma unroll
    for (int m = 0; m < 4; ++m)
      af[m] = *(const short8*)(&SA[cur][0] + ((ww * 4 + m) * 64 + lane) * 8);
#pragma unroll
    for (int n = 0; n < 4; ++n)
      bf[n] = *(const short8*)(&SB[cur][0] + ((wx * 4 + n) * 64 + lane) * 8);

    __builtin_amdgcn_s_setprio(1);
#pragma unroll
    for (int m = 0; m < 4; ++m)
#pragma unroll
      for (int n = 0; n < 4; ++n)
        acc[m][n] = __builtin_amdgcn_mfma_f32_16x16x32_bf16(af[m], bf[n], acc[m][n], 0, 0, 0);
    __builtin_amdgcn_s_setprio(0);
  }

  // ---- epilogue: non-temporal float4 stores + fused d2 mins ----
  float rmin[4];                      // per n (x-rows)
  float cmin[4][4];                   // per m,j (w-cols)
#pragma unroll
  for (int n = 0; n < 4; ++n) rmin[n] = 1e30f;
#pragma unroll
  for (int m = 0; m < 4; ++m)
#pragma unroll
    for (int j = 0; j < 4; ++j) cmin[m][j] = 1e30f;

  const float* w2p = w2 + w0 + ww * 64;
#pragma unroll
  for (int m = 0; m < 4; ++m) {
    float4 w2v = *(const float4*)(w2p + m * 16 + q * 4);
    const size_t wcol = (size_t)(w0 + ww * 64 + m * 16 + q * 4);
#pragma unroll
    for (int n = 0; n < 4; ++n) {
      f32x4 c = acc[m][n];
      int xr = x0 + wx * 64 + n * 16 + r16;
      __builtin_nontemporal_store(c, (f32x4*)&Cout[(size_t)xr * P_DIM + wcol]);
      float d0 = fmaxf(fmaf(-2.f, c[0], 1.f + w2v.x), 0.f);
      float d1 = fmaxf(fmaf(-2.f, c[1], 1.f + w2v.y), 0.f);
      float d2 = fmaxf(fmaf(-2.f, c[2], 1.f + w2v.z), 0.f);
      float d3 = fmaxf(fmaf(-2.f, c[3], 1.f + w2v.w), 0.f);
      rmin[n] = fminf(rmin[n], fminf(fminf(d0, d1), fminf(d2, d3)));
      cmin[m][0] = fminf(cmin[m][0], d0);
      cmin[m][1] = fminf(cmin[m][1], d1);
      cmin[m][2] = fminf(cmin[m][2], d2);
      cmin[m][3] = fminf(cmin[m][3], d3);
    }
  }
  // row-min: reduce across q (same x-row for equal r16)
#pragma unroll
  for (int mask = 16; mask <= 32; mask <<= 1)
#pragma unroll
    for (int n = 0; n < 4; ++n)
      rmin[n] = fminf(rmin[n], __shfl_xor(rmin[n], mask));
  if (q == 0) {
#pragma unroll
    for (int n = 0; n < 4; ++n)
      atomicMin(&rowmin_u[wx * 64 + n * 16 + r16], __float_as_uint(rmin[n]));
  }
  // col-min: reduce across r16 (same w-col for equal q)
#pragma unroll
  for (int mask = 1; mask <= 8; mask <<= 1)
#pragma unroll
    for (int m = 0; m < 4; ++m)
#pragma unroll
      for (int j = 0; j < 4; ++j)
        cmin[m][j] = fminf(cmin[m][j], __shfl_xor(cmin[m][j], mask));
  if (r16 == 0) {
#pragma unroll
    for (int m = 0; m < 4; ++m)
#pragma unroll
      for (int j = 0; j < 4; ++j)
        atomicMin(&colmin_u[ww * 64 + m * 16 + q * 4 + j], __float_as_uint(cmin[m][j]));
  }
  __syncthreads();
  if (tid < 128) atomicMin(&rowmin_g[x0 + tid], rowmin_u[tid]);
  else           atomicMin(&colmin_g[w0 + (tid - 128)], colmin_u[tid - 128]);
}

// ---------------------------------------------------------------------------
// Combined reduce: bid<128 -> row mins chunk; bid>=128 -> col mins chunk.
// sqrt + fixed-order block sums (deterministic).
// ---------------------------------------------------------------------------
__global__ __launch_bounds__(256) void minsqrt_sum(const unsigned int* __restrict__ rmins,
                                                   const unsigned int* __restrict__ cmins,
                                                   float* __restrict__ rowsums,
                                                   float* __restrict__ colsums) {
  int bid = blockIdx.x;
  const unsigned int* src = (bid < 128) ? (rmins + bid * 256) : (cmins + (bid - 128) * 256);
  float s = sqrtf(__uint_as_float(src[threadIdx.x]));
#pragma unroll
  for (int mask = 1; mask < 64; mask <<= 1) s += __shfl_xor(s, mask);
  __shared__ float wsum[4];
  int wave = threadIdx.x >> 6, lane = threadIdx.x & 63;
  if (lane == 0) wsum[wave] = s;
  __syncthreads();
  if (threadIdx.x == 0) {
    float t = wsum[0] + wsum[1] + wsum[2] + wsum[3];
    if (bid < 128) rowsums[bid] = t; else colsums[bid - 128] = t;
  }
}

__global__ void finalize_kernel(const float* __restrict__ rowp, const float* __restrict__ colp,
                                const float* __restrict__ recon, const float* __restrict__ kl,
                                const float* __restrict__ mmd, float* __restrict__ out) {
  int lane = threadIdx.x;  // 64 threads
  float rs = rowp[lane] + rowp[lane + 64];
  float cs = (lane < 16) ? colp[lane] : 0.0f;
#pragma unroll
  for (int mask = 1; mask < 64; mask <<= 1) {
    rs += __shfl_xor(rs, mask);
    cs += __shfl_xor(cs, mask);
  }
  if (lane == 0) {
    out[OUT_CVAE] = recon[0] + 0.5f * kl[0] + mmd[0];
    out[OUT_PROT] = 0.5f * (rs / (float)N_ROWS) + 0.5f * (cs / (float)P_DIM);
  }
}

extern "C" void kernel_launch(void* const* d_in, const int* in_sizes, int n_in,
                              void* d_out, int out_size, void* d_ws, size_t ws_size,
                              hipStream_t stream) {
  const float* x     = (const float*)d_in[0];
  const float* W     = (const float*)d_in[1];
  const float* recon = (const float*)d_in[2];
  const float* kl    = (const float*)d_in[3];
  const float* mmd   = (const float*)d_in[4];
  float* out    = (float*)d_out;
  float* xn     = out;
  float* logits = out + OUT_LOGITS;

  char* ws = (char*)d_ws;
  unsigned short* Xbf = (unsigned short*)ws;                 // 33,554,432 B
  unsigned short* Wbf = (unsigned short*)(ws + 33554432);    //  4,194,304 B
  float* w2          = (float*)(ws + 37748736);              //     16,384 B
  unsigned int* rmg  = (unsigned int*)(ws + 37765120);       //    131,072 B (32768)
  unsigned int* cmg  = (unsigned int*)(ws + 37896192);       //     16,384 B (4096)
  float* rowsums     = (float*)(ws + 37912576);              //        512 B (128)
  float* colsums     = (float*)(ws + 37913088);              //         64 B (16)

  prep_kernel<1><<<N_ROWS / 4, 256, 0, stream>>>(x, xn, Xbf, nullptr, rmg, cmg);
  prep_kernel<0><<<P_DIM / 4, 256, 0, stream>>>(W, nullptr, Wbf, w2, nullptr, nullptr);
  gemm_fused<<<(N_ROWS / 128) * (P_DIM / 128), 256, 0, stream>>>(
      Wbf, Xbf, w2, logits, rmg, cmg);
  minsqrt_sum<<<144, 256, 0, stream>>>(rmg, cmg, rowsums, colsums);
  finalize_kernel<<<1, 64, 0, stream>>>(rowsums, colsums, recon, kl, mmd, out);
}

// Round 13
// 246.746 us; speedup vs baseline: 5.8422x; 1.0221x over previous
//
#include <hip/hip_runtime.h>

#define N_ROWS 32768
#define D_DIM  512
#define P_DIM  4096

#define OUT_LOGITS (32768LL * 512)
#define OUT_CVAE   (OUT_LOGITS + 32768LL * 4096)
#define OUT_PROT   (OUT_CVAE + 1)

typedef __attribute__((ext_vector_type(8))) short short8;
typedef __attribute__((ext_vector_type(4))) float f32x4;

__device__ __forceinline__ unsigned short f2bf(float f) {
  unsigned u = __float_as_uint(f);
  u = (u + 0x7FFFu + ((u >> 16) & 1u)) >> 16;
  return (unsigned short)u;
}

__device__ __forceinline__ void gload16(const void* g, void* l) {
  __builtin_amdgcn_global_load_lds((const __attribute__((address_space(1))) void*)g,
                                   (__attribute__((address_space(3))) void*)l,
                                   16, 0, 0);
}

// ---------------------------------------------------------------------------
// Prep: row L2-norm; bf16 copy in 128-row-tile fragment-major layout
// (R5/R7 verified). NORM=1 additionally initializes the global min arrays.
// xn uses non-temporal stores.
// ---------------------------------------------------------------------------
template <int NORM>
__global__ __launch_bounds__(256) void prep_kernel(const float* __restrict__ in,
                                                   float* __restrict__ outf,
                                                   unsigned short* __restrict__ outb,
                                                   float* __restrict__ n2,
                                                   unsigned int* __restrict__ rmg,
                                                   unsigned int* __restrict__ cmg) {
  if (NORM) {
    int bid = blockIdx.x;
    if (bid < 128)      rmg[bid * 256 + threadIdx.x] = 0x7F800000u;
    else if (bid < 144) cmg[(bid - 128) * 256 + threadIdx.x] = 0x7F800000u;
  }
  int wave = threadIdx.x >> 6, lane = threadIdx.x & 63;
  int row  = blockIdx.x * 4 + wave;
  const float* p = in + (size_t)row * D_DIM + lane * 8;
  float4 v0 = *(const float4*)p;
  float4 v1 = *(const float4*)(p + 4);
  float ss = v0.x*v0.x + v0.y*v0.y + v0.z*v0.z + v0.w*v0.w
           + v1.x*v1.x + v1.y*v1.y + v1.z*v1.z + v1.w*v1.w;
#pragma unroll
  for (int m = 1; m < 64; m <<= 1) ss += __shfl_xor(ss, m);
  if (NORM) {
    float rinv = 1.0f / fmaxf(sqrtf(ss), 1e-12f);
    v0.x *= rinv; v0.y *= rinv; v0.z *= rinv; v0.w *= rinv;
    v1.x *= rinv; v1.y *= rinv; v1.z *= rinv; v1.w *= rinv;
    f32x4* qp = (f32x4*)(outf + (size_t)row * D_DIM + lane * 8);
    f32x4 a0 = {v0.x, v0.y, v0.z, v0.w};
    f32x4 a1 = {v1.x, v1.y, v1.z, v1.w};
    __builtin_nontemporal_store(a0, qp);
    __builtin_nontemporal_store(a1, qp + 1);
  } else {
    if (lane == 0) n2[row] = ss;
  }
  uint4 b;
  b.x = (unsigned)f2bf(v0.x) | ((unsigned)f2bf(v0.y) << 16);
  b.y = (unsigned)f2bf(v0.z) | ((unsigned)f2bf(v0.w) << 16);
  b.z = (unsigned)f2bf(v1.x) | ((unsigned)f2bf(v1.y) << 16);
  b.w = (unsigned)f2bf(v1.z) | ((unsigned)f2bf(v1.w) << 16);
  int tile = row >> 7, fr = (row >> 4) & 7, r = row & 15;
  size_t dst = (size_t)(tile * 16 + (lane >> 2)) * 4096
             + (size_t)((fr * 64 + (lane & 3) * 16 + r) * 8);
  *(uint4*)(outb + dst) = b;
}

// ---------------------------------------------------------------------------
// 128x128-tile GEMM: 4 waves, BK=32, DOUBLE-buffered LDS (2 x 16 KB = 33 KB
// total) -> 4 blocks/CU (launch_bounds(256,4), VGPR cap 128 — acc 64 + frags
// 32 + addr ~20 fits; R4 compiled this tile at exactly 128, no spill).
// One s_barrier + vmcnt(0) per K-step; the waited stage was issued a full
// step earlier and 4-block stagger covers the residual. WAR-safe: stg(kt+1)
// writes the buffer last read at kt-1; all waves past barrier(kt) have
// completed those reads.
// A = W-frag, B = xn-frag -> lane's f32x4 spans 4 consecutive logits cols ->
// NT dwordx4 stores. Fused d2 epilogue -> global atomicMin (deterministic).
// ---------------------------------------------------------------------------
__global__ __launch_bounds__(256, 4) void gemm_fused(
    const unsigned short* __restrict__ Wb, const unsigned short* __restrict__ Xb,
    const float* __restrict__ w2, float* __restrict__ Cout,
    unsigned int* __restrict__ rowmin_g, unsigned int* __restrict__ colmin_g) {
  __shared__ __align__(16) unsigned short SA[2][4096];   // W tile 128x32
  __shared__ __align__(16) unsigned short SB[2][4096];   // x tile 128x32
  __shared__ unsigned int rowmin_u[128];                 // per x-row
  __shared__ unsigned int colmin_u[128];                 // per w-col

  const int tid = threadIdx.x;
  const int wave = tid >> 6, lane = tid & 63;
  const int q = lane >> 4, r16 = lane & 15;
  const int ww = wave >> 1, wx = wave & 1;

  const int b = blockIdx.x;
  const int tw = (b & 7) * 4 + ((b >> 3) & 3);   // 0..31 (XCD-pinned W column)
  const int tx = b >> 5;                         // 0..255
  const int w0 = tw * 128, x0 = tx * 128;

  if (tid < 128) { rowmin_u[tid] = 0x7F800000u; colmin_u[tid] = 0x7F800000u; }

  const unsigned short* Wg = Wb + (size_t)(tw * 16) * 4096;
  const unsigned short* Xg = Xb + (size_t)(tx * 16) * 4096;

  f32x4 acc[4][4];
#pragma unroll
  for (int m = 0; m < 4; ++m)
#pragma unroll
    for (int n = 0; n < 4; ++n) acc[m][n] = (f32x4){0.f, 0.f, 0.f, 0.f};

  auto stg = [&](int kt, int bu) {   // 4 gload_lds per thread
#pragma unroll
    for (int i = 0; i < 2; ++i) {
      int c = (tid + 256 * i) * 8;
      gload16(Wg + (size_t)kt * 4096 + c, &SA[bu][0] + c);
      gload16(Xg + (size_t)kt * 4096 + c, &SB[bu][0] + c);
    }
  };

  stg(0, 0);

#pragma unroll
  for (int kt = 0; kt < 16; ++kt) {
    const int cur = kt & 1;
    asm volatile("s_waitcnt vmcnt(0)" ::: "memory");   // stg(kt), issued 1 step ago
    __builtin_amdgcn_s_barrier();

    if (kt < 15) stg(kt + 1, cur ^ 1);   // buffer last read at kt-1: WAR-safe

    short8 af[4], bf[4];
#pragma unroll
    for (int m = 0; m < 4; ++m)
      af[m] = *(const short8*)(&SA[cur][0] + ((ww * 4 + m) * 64 + lane) * 8);
#pragma unroll
    for (int n = 0; n < 4; ++n)
      bf[n] = *(const short8*)(&SB[cur][0] + ((wx * 4 + n) * 64 + lane) * 8);

    __builtin_amdgcn_s_setprio(1);
#pragma unroll
    for (int m = 0; m < 4; ++m)
#pragma unroll
      for (int n = 0; n < 4; ++n)
        acc[m][n] = __builtin_amdgcn_mfma_f32_16x16x32_bf16(af[m], bf[n], acc[m][n], 0, 0, 0);
    __builtin_amdgcn_s_setprio(0);
  }

  // ---- epilogue: non-temporal float4 stores + fused d2 mins ----
  float rmin[4];                      // per n (x-rows)
  float cmin[4][4];                   // per m,j (w-cols)
#pragma unroll
  for (int n = 0; n < 4; ++n) rmin[n] = 1e30f;
#pragma unroll
  for (int m = 0; m < 4; ++m)
#pragma unroll
    for (int j = 0; j < 4; ++j) cmin[m][j] = 1e30f;

  const float* w2p = w2 + w0 + ww * 64;
#pragma unroll
  for (int m = 0; m < 4; ++m) {
    float4 w2v = *(const float4*)(w2p + m * 16 + q * 4);
    const size_t wcol = (size_t)(w0 + ww * 64 + m * 16 + q * 4);
#pragma unroll
    for (int n = 0; n < 4; ++n) {
      f32x4 c = acc[m][n];
      int xr = x0 + wx * 64 + n * 16 + r16;
      __builtin_nontemporal_store(c, (f32x4*)&Cout[(size_t)xr * P_DIM + wcol]);
      float d0 = fmaxf(fmaf(-2.f, c[0], 1.f + w2v.x), 0.f);
      float d1 = fmaxf(fmaf(-2.f, c[1], 1.f + w2v.y), 0.f);
      float d2 = fmaxf(fmaf(-2.f, c[2], 1.f + w2v.z), 0.f);
      float d3 = fmaxf(fmaf(-2.f, c[3], 1.f + w2v.w), 0.f);
      rmin[n] = fminf(rmin[n], fminf(fminf(d0, d1), fminf(d2, d3)));
      cmin[m][0] = fminf(cmin[m][0], d0);
      cmin[m][1] = fminf(cmin[m][1], d1);
      cmin[m][2] = fminf(cmin[m][2], d2);
      cmin[m][3] = fminf(cmin[m][3], d3);
    }
  }
  // row-min: reduce across q (same x-row for equal r16)
#pragma unroll
  for (int mask = 16; mask <= 32; mask <<= 1)
#pragma unroll
    for (int n = 0; n < 4; ++n)
      rmin[n] = fminf(rmin[n], __shfl_xor(rmin[n], mask));
  if (q == 0) {
#pragma unroll
    for (int n = 0; n < 4; ++n)
      atomicMin(&rowmin_u[wx * 64 + n * 16 + r16], __float_as_uint(rmin[n]));
  }
  // col-min: reduce across r16 (same w-col for equal q)
#pragma unroll
  for (int mask = 1; mask <= 8; mask <<= 1)
#pragma unroll
    for (int m = 0; m < 4; ++m)
#pragma unroll
      for (int j = 0; j < 4; ++j)
        cmin[m][j] = fminf(cmin[m][j], __shfl_xor(cmin[m][j], mask));
  if (r16 == 0) {
#pragma unroll
    for (int m = 0; m < 4; ++m)
#pragma unroll
      for (int j = 0; j < 4; ++j)
        atomicMin(&colmin_u[ww * 64 + m * 16 + q * 4 + j], __float_as_uint(cmin[m][j]));
  }
  __syncthreads();
  if (tid < 128) atomicMin(&rowmin_g[x0 + tid], rowmin_u[tid]);
  else           atomicMin(&colmin_g[w0 + (tid - 128)], colmin_u[tid - 128]);
}

// ---------------------------------------------------------------------------
// Combined reduce: bid<128 -> row mins chunk; bid>=128 -> col mins chunk.
// sqrt + fixed-order block sums (deterministic).
// ---------------------------------------------------------------------------
__global__ __launch_bounds__(256) void minsqrt_sum(const unsigned int* __restrict__ rmins,
                                                   const unsigned int* __restrict__ cmins,
                                                   float* __restrict__ rowsums,
                                                   float* __restrict__ colsums) {
  int bid = blockIdx.x;
  const unsigned int* src = (bid < 128) ? (rmins + bid * 256) : (cmins + (bid - 128) * 256);
  float s = sqrtf(__uint_as_float(src[threadIdx.x]));
#pragma unroll
  for (int mask = 1; mask < 64; mask <<= 1) s += __shfl_xor(s, mask);
  __shared__ float wsum[4];
  int wave = threadIdx.x >> 6, lane = threadIdx.x & 63;
  if (lane == 0) wsum[wave] = s;
  __syncthreads();
  if (threadIdx.x == 0) {
    float t = wsum[0] + wsum[1] + wsum[2] + wsum[3];
    if (bid < 128) rowsums[bid] = t; else colsums[bid - 128] = t;
  }
}

__global__ void finalize_kernel(const float* __restrict__ rowp, const float* __restrict__ colp,
                                const float* __restrict__ recon, const float* __restrict__ kl,
                                const float* __restrict__ mmd, float* __restrict__ out) {
  int lane = threadIdx.x;  // 64 threads
  float rs = rowp[lane] + rowp[lane + 64];
  float cs = (lane < 16) ? colp[lane] : 0.0f;
#pragma unroll
  for (int mask = 1; mask < 64; mask <<= 1) {
    rs += __shfl_xor(rs, mask);
    cs += __shfl_xor(cs, mask);
  }
  if (lane == 0) {
    out[OUT_CVAE] = recon[0] + 0.5f * kl[0] + mmd[0];
    out[OUT_PROT] = 0.5f * (rs / (float)N_ROWS) + 0.5f * (cs / (float)P_DIM);
  }
}

extern "C" void kernel_launch(void* const* d_in, const int* in_sizes, int n_in,
                              void* d_out, int out_size, void* d_ws, size_t ws_size,
                              hipStream_t stream) {
  const float* x     = (const float*)d_in[0];
  const float* W     = (const float*)d_in[1];
  const float* recon = (const float*)d_in[2];
  const float* kl    = (const float*)d_in[3];
  const float* mmd   = (const float*)d_in[4];
  float* out    = (float*)d_out;
  float* xn     = out;
  float* logits = out + OUT_LOGITS;

  char* ws = (char*)d_ws;
  unsigned short* Xbf = (unsigned short*)ws;                 // 33,554,432 B
  unsigned short* Wbf = (unsigned short*)(ws + 33554432);    //  4,194,304 B
  float* w2          = (float*)(ws + 37748736);              //     16,384 B
  unsigned int* rmg  = (unsigned int*)(ws + 37765120);       //    131,072 B (32768)
  unsigned int* cmg  = (unsigned int*)(ws + 37896192);       //     16,384 B (4096)
  float* rowsums     = (float*)(ws + 37912576);              //        512 B (128)
  float* colsums     = (float*)(ws + 37913088);              //         64 B (16)

  prep_kernel<1><<<N_ROWS / 4, 256, 0, stream>>>(x, xn, Xbf, nullptr, rmg, cmg);
  prep_kernel<0><<<P_DIM / 4, 256, 0, stream>>>(W, nullptr, Wbf, w2, nullptr, nullptr);
  gemm_fused<<<(N_ROWS / 128) * (P_DIM / 128), 256, 0, stream>>>(
      Wbf, Xbf, w2, logits, rmg, cmg);
  minsqrt_sum<<<144, 256, 0, stream>>>(rmg, cmg, rowsums, colsums);
  finalize_kernel<<<1, 64, 0, stream>>>(rowsums, colsums, recon, kl, mmd, out);
}